// Round 11
// baseline (1144.536 us; speedup 1.0000x reference)
//
#include <hip/hip_runtime.h>
#include <math.h>

#define NB 16
#define DIMD 256
#define NHH 8
#define NLAT 64
#define EMAXC 13568
#define NCH2 14            /* chunks of 1024 events (last partial) */
#define EPAD (NCH2*1024)   /* 14336: padded event stride (bytes for fp8 PT/VT) */

typedef float f32x4 __attribute__((ext_vector_type(4)));
typedef __bf16 bf16x8 __attribute__((ext_vector_type(8)));
typedef unsigned short u16;
typedef unsigned char u8;
typedef __attribute__((ext_vector_type(8))) unsigned short u16x8;

static __device__ __forceinline__ float wave_sum(float v){
#pragma unroll
  for (int off = 32; off > 0; off >>= 1) v += __shfl_xor(v, off, 64);
  return v;
}

static __device__ __forceinline__ u16 f2bf(float x){
  unsigned u = __float_as_uint(x);
  u += 0x7fffu + ((u >> 16) & 1u);
  return (u16)(u >> 16);
}

static __device__ __forceinline__ float gelu_tanh(float x){
  float x3 = x*x*x;
  return 0.5f*x*(1.0f + tanhf(0.7978845608028654f*(x + 0.044715f*x3)));
}

__global__ void k_zero(int* cnt){ if ((int)threadIdx.x < NB) cnt[threadIdx.x] = 0; }

// LDS-histogram bucket sort: 16 global atomics per 1024-event block.
__global__ void k_sort(const int* __restrict__ bidx, int* __restrict__ cnt,
                       int* __restrict__ sorted, int E){
  __shared__ int h[NB], base[NB];
  int t = threadIdx.x;
  if (t < NB) h[t] = 0;
  __syncthreads();
  int e0 = blockIdx.x*1024;
  int myb[4], myp[4];
#pragma unroll
  for (int i = 0; i < 4; i++){
    int e = e0 + i*256 + t;
    myb[i] = -1;
    if (e < E){ myb[i] = bidx[e]; myp[i] = atomicAdd(&h[myb[i]], 1); }
  }
  __syncthreads();
  if (t < NB) base[t] = atomicAdd(&cnt[t], h[t]);
  __syncthreads();
#pragma unroll
  for (int i = 0; i < 4; i++){
    if (myb[i] >= 0){
      int p = base[myb[i]] + myp[i];
      if (p < EMAXC) sorted[myb[i]*EMAXC + p] = e0 + i*256 + t;
    }
  }
}

// LayerNorm over rows of 256 (used only for lat_init prep).
__global__ void k_ln(const float* __restrict__ X, float* __restrict__ Y, int rows){
  int wave = threadIdx.x >> 6, lane = threadIdx.x & 63;
  int row = blockIdx.x*4 + wave;
  if (row >= rows) return;
  float4 x = ((const float4*)(X + (size_t)row*DIMD))[lane];
  float s = wave_sum(x.x + x.y + x.z + x.w);
  float m = s * (1.0f/DIMD);
  float d0 = x.x-m, d1 = x.y-m, d2 = x.z-m, d3 = x.w-m;
  float v = wave_sum(d0*d0 + d1*d1 + d2*d2 + d3*d3) * (1.0f/DIMD);
  float rs = rsqrtf(v + 1e-5f);
  ((float4*)(Y + (size_t)row*DIMD))[lane] = make_float4(d0*rs, d1*rs, d2*rs, d3*rs);
}

// lat[row] = lat_init[row % 64]  (row-broadcast residual init)
__global__ void k_init(const float* __restrict__ lat_i, float* __restrict__ lat){
  int r = blockIdx.x, t = threadIdx.x;
  lat[(size_t)r*DIMD + t] = lat_i[(size_t)(r & 63)*DIMD + t];
}

// Small prep GEMM (tiny M): C[M,N] = A[M,K] @ W[K,N]
__global__ __launch_bounds__(256) void k_gemm(
    const float* __restrict__ A, const float* __restrict__ W,
    float* __restrict__ C, int M, int K, int N){
  __shared__ float As[8][1024];
  int t = threadIdx.x;
  int row0 = blockIdx.x*8;
  int col = blockIdx.y*256 + t;
  int kq = K >> 2;
  for (int idx = t; idx < 8*kq; idx += 256){
    int r = idx / kq, kc = idx % kq;
    float4 v = make_float4(0.f,0.f,0.f,0.f);
    if (row0 + r < M) v = ((const float4*)(A + (size_t)(row0+r)*K))[kc];
    ((float4*)&As[r][0])[kc] = v;
  }
  __syncthreads();
  float acc[8] = {0,0,0,0,0,0,0,0};
  for (int k = 0; k < K; k += 4){
    float w0 = W[(size_t)(k+0)*N + col];
    float w1 = W[(size_t)(k+1)*N + col];
    float w2 = W[(size_t)(k+2)*N + col];
    float w3 = W[(size_t)(k+3)*N + col];
#pragma unroll
    for (int r = 0; r < 8; r++){
      float4 a = *((const float4*)&As[r][k]);
      acc[r] += a.x*w0 + a.y*w1 + a.z*w2 + a.w*w3;
    }
  }
#pragma unroll
  for (int r = 0; r < 8; r++){
    int row = row0 + r;
    if (row < M) C[(size_t)row*N + col] = acc[r];
  }
}

// Tiled f32 GEMM for the latent chain. 64x64 tile, BK=32, 256 thr, 4x4/thread.
// grid (M/64, N/64, S): K split into S chunks.
// mode 0: C = A@W ; 1: gelu ; 2: atomicAdd(C, A@W).
// do_ln (requires K==256, S==1): LayerNorm rows of A (optional affine lnw/lnb).
__global__ __launch_bounds__(256) void k_gemm2(
    const float* __restrict__ A, const float* __restrict__ W, float* __restrict__ C,
    const float* __restrict__ lnw, const float* __restrict__ lnb,
    int M, int K, int N, int mode, int do_ln){
  __shared__ float As[32][66];
  __shared__ float Bs[32][66];
  __shared__ float lnm[64], lnr[64];
  const int t = threadIdx.x;
  const int m0 = blockIdx.x*64, n0 = blockIdx.y*64;
  const int Kc = K / gridDim.z;
  const int k0b = blockIdx.z*Kc;
  const int ty = t >> 4, tx = t & 15;
  float acc[4][4];
#pragma unroll
  for (int i = 0; i < 4; i++)
#pragma unroll
    for (int j = 0; j < 4; j++) acc[i][j] = 0.f;

  if (do_ln){
    int r = t >> 2, seg = (t & 3)*64;
    const float* Ar = A + (size_t)(m0 + r)*K + seg;
    float s = 0.f, s2 = 0.f;
#pragma unroll
    for (int j = 0; j < 64; j += 4){
      float4 v = *(const float4*)(Ar + j);
      s  += v.x + v.y + v.z + v.w;
      s2 += v.x*v.x + v.y*v.y + v.z*v.z + v.w*v.w;
    }
    s += __shfl_xor(s, 1, 64); s2 += __shfl_xor(s2, 1, 64);
    s += __shfl_xor(s, 2, 64); s2 += __shfl_xor(s2, 2, 64);
    if ((t & 3) == 0){
      float m = s*(1.0f/256.0f);
      float var = s2*(1.0f/256.0f) - m*m;
      lnm[r] = m; lnr[r] = rsqrtf(var + 1e-5f);
    }
  }
  if (do_ln) __syncthreads();

  for (int k0 = k0b; k0 < k0b + Kc; k0 += 32){
    __syncthreads();
#pragma unroll
    for (int p = 0; p < 2; p++){
      int li = t + p*256;
      int r = li >> 3, kc = li & 7;
      float4 va = *(const float4*)(A + (size_t)(m0+r)*K + k0 + kc*4);
      if (do_ln){
        float m = lnm[r], rs = lnr[r];
        va.x = (va.x - m)*rs; va.y = (va.y - m)*rs;
        va.z = (va.z - m)*rs; va.w = (va.w - m)*rs;
        if (lnw){
          int k = k0 + kc*4;
          va.x = va.x*lnw[k+0] + lnb[k+0];
          va.y = va.y*lnw[k+1] + lnb[k+1];
          va.z = va.z*lnw[k+2] + lnb[k+2];
          va.w = va.w*lnw[k+3] + lnb[k+3];
        }
      }
      As[kc*4+0][r] = va.x; As[kc*4+1][r] = va.y;
      As[kc*4+2][r] = va.z; As[kc*4+3][r] = va.w;
      int kr = li >> 4, nc = li & 15;
      *(float4*)&Bs[kr][nc*4] = *(const float4*)(W + (size_t)(k0+kr)*N + n0 + nc*4);
    }
    __syncthreads();
#pragma unroll
    for (int k = 0; k < 32; k++){
      float4 a = *(const float4*)&As[k][ty*4];
      float4 b = *(const float4*)&Bs[k][tx*4];
      acc[0][0] += a.x*b.x; acc[0][1] += a.x*b.y; acc[0][2] += a.x*b.z; acc[0][3] += a.x*b.w;
      acc[1][0] += a.y*b.x; acc[1][1] += a.y*b.y; acc[1][2] += a.y*b.z; acc[1][3] += a.y*b.w;
      acc[2][0] += a.z*b.x; acc[2][1] += a.z*b.y; acc[2][2] += a.z*b.z; acc[2][3] += a.z*b.w;
      acc[3][0] += a.w*b.x; acc[3][1] += a.w*b.y; acc[3][2] += a.w*b.z; acc[3][3] += a.w*b.w;
    }
  }
#pragma unroll
  for (int i = 0; i < 4; i++){
    int row = m0 + ty*4 + i;
    float* crow = C + (size_t)row*N + n0 + tx*4;
#pragma unroll
    for (int j = 0; j < 4; j++){
      float v = acc[i][j];
      if (mode == 1) v = gelu_tanh(v);
      if (mode == 2) atomicAdd(&crow[j], v);
      else crow[j] = v;
    }
  }
}

// Build Wt[768][256] bf16 (transposed, column-reordered)
__global__ void k_qw(const float* __restrict__ Wkv, const float* __restrict__ qc,
                     u16* __restrict__ Wt){
  int n = blockIdx.x;
  int k = threadIdx.x;
  float v;
  if (n < 256){
    v = Wkv[(size_t)k*512 + 256 + n];
  } else {
    int h = (n - 256) >> 6, l = (n - 256) & 63;
    const float* wk = Wkv + (size_t)k*512 + h*32;
    const float* qr = qc + (size_t)l*256 + h*32;
    float s = 0.f;
#pragma unroll
    for (int dd = 0; dd < 32; dd++) s += wk[dd]*qr[dd];
    v = s*0.1767766952966369f;
  }
  Wt[(size_t)n*256 + k] = f2bf(v);
}

// Gather+LN -> XLN bf16 (group-local), zero pad rows. One wave per event row.
__global__ void k_a0(const int* __restrict__ sorted, const int* __restrict__ cnt,
                     const int* __restrict__ nid, const int* __restrict__ tbin,
                     const int* __restrict__ vval,
                     const float* __restrict__ ne, const float* __restrict__ te,
                     const float* __restrict__ ve, u16* __restrict__ XLN, int b0){
  int wv = threadIdx.x >> 6, lane = threadIdx.x & 63;
  int e = blockIdx.x*4 + wv;
  int bg = blockIdx.y, b = b0 + bg;
  int cn = min(cnt[b], EMAXC);
  ushort4 pk; pk.x = 0; pk.y = 0; pk.z = 0; pk.w = 0;
  if (e < cn){
    int ev = sorted[b*EMAXC + e];
    float4 aa = ((const float4*)(ne + (size_t)nid[ev]*DIMD))[lane];
    float4 bb = ((const float4*)(te + (size_t)tbin[ev]*DIMD))[lane];
    float4 cc = ((const float4*)(ve + (size_t)vval[ev]*DIMD))[lane];
    float x0 = aa.x+bb.x+cc.x, x1 = aa.y+bb.y+cc.y;
    float x2 = aa.z+bb.z+cc.z, x3 = aa.w+bb.w+cc.w;
    float s = wave_sum(x0 + x1 + x2 + x3);
    float m = s*(1.0f/DIMD);
    x0 -= m; x1 -= m; x2 -= m; x3 -= m;
    float v = wave_sum(x0*x0 + x1*x1 + x2*x2 + x3*x3)*(1.0f/DIMD);
    float rs = rsqrtf(v + 1e-5f);
    pk.x = f2bf(x0*rs); pk.y = f2bf(x1*rs); pk.z = f2bf(x2*rs); pk.w = f2bf(x3*rs);
  }
  *(ushort4*)(XLN + ((size_t)bg*EMAXC + e)*DIMD + lane*4) = pk;
}

// Dense MFMA GEMM: [PT|VT] (transposed, fp8 e4m3) = exp?(XLN @ Wt^T).
// 128x128 tile, BK=32 double-buffered (register prefetch -> ping-pong LDS,
// ONE barrier per K-step, global-load latency hidden under MFMA).
// Pitch 36 u16 = 18 dwords: 18r mod 32 distinct over 16 rows -> conflict-free
// fragment reads. LDS exactly 36 KB -> 4 blocks/CU. Tr overlays Xs.
// grid (48, 14, gb), XCD-affinity swizzle.
__global__ __launch_bounds__(256) void k_a(
    const u16* __restrict__ XLN, const u16* __restrict__ Wt,
    const int* __restrict__ cnt, u8* __restrict__ PT, u8* __restrict__ VT, int b0)
{
  __shared__ union ShMem {
    struct { u16 Xs[2][128][36]; u16 Ws[2][128][36]; } s;
    u8 Tr[128][136];
  } sh;
  const int t = threadIdx.x;
  const int wv = t >> 6, lane = t & 63;
  const int quad = lane >> 4, lane15 = lane & 15;
  const int nidx = blockIdx.x >> 3;
  const int rtile = blockIdx.y*8 + (blockIdx.x & 7);
  if (nidx >= 6 || rtile >= EMAXC/128) return;
  const int bg = blockIdx.z;
  const int b = b0 + bg;
  const int cn = min(cnt[b], EMAXC);
  const int row0 = rtile * 128;
  if (row0 >= cn) return;
  const int n0 = nidx * 128;
  const int eh = (wv >> 1) * 64, nh = (wv & 1) * 64;

  f32x4 acc[4][4];
#pragma unroll
  for (int i = 0; i < 4; i++)
#pragma unroll
    for (int j = 0; j < 4; j++) acc[i][j] = (f32x4){0.f,0.f,0.f,0.f};

  const u16* Xbase = XLN + ((size_t)bg*EMAXC + row0)*DIMD;
  const u16* Wbase = Wt + (size_t)n0*256;
  const int sr = t >> 1, skc = t & 1;   // li = p*256+t -> r = (p*256+t)>>2 ... use per-p below

  u16x8 xv[2], wvv[2];
  auto gload = [&](int k0){
#pragma unroll
    for (int p = 0; p < 2; p++){
      int li = p*256 + t;
      int r = li >> 2, kc = li & 3;
      xv[p]  = *(const u16x8*)(Xbase + (size_t)r*DIMD + k0 + kc*8);
      wvv[p] = *(const u16x8*)(Wbase + (size_t)r*256  + k0 + kc*8);
    }
  };
  auto sstore = [&](int buf){
#pragma unroll
    for (int p = 0; p < 2; p++){
      int li = p*256 + t;
      int r = li >> 2, kc = li & 3;
      *(u16x8*)&sh.s.Xs[buf][r][kc*8] = xv[p];
      *(u16x8*)&sh.s.Ws[buf][r][kc*8] = wvv[p];
    }
  };
  auto compute = [&](int buf){
    bf16x8 a[4], bw[4];
#pragma unroll
    for (int mt = 0; mt < 4; mt++)
      a[mt] = *(const bf16x8*)&sh.s.Xs[buf][eh + mt*16 + lane15][quad*8];
#pragma unroll
    for (int nt = 0; nt < 4; nt++)
      bw[nt] = *(const bf16x8*)&sh.s.Ws[buf][nh + nt*16 + lane15][quad*8];
#pragma unroll
    for (int mt = 0; mt < 4; mt++)
#pragma unroll
      for (int nt = 0; nt < 4; nt++)
        acc[mt][nt] = __builtin_amdgcn_mfma_f32_16x16x32_bf16(a[mt], bw[nt], acc[mt][nt], 0, 0, 0);
  };

  (void)sr; (void)skc;
  gload(0);
  sstore(0);
#pragma unroll
  for (int it = 0; it < 8; it++){
    int buf = it & 1;
    if (it < 7) gload((it + 1)*32);
    __syncthreads();          // buf's stores visible; all waves done with compute(it-1)
    compute(buf);
    if (it < 7) sstore(1 - buf);
  }
  const int is_p = (n0 >= 256);
  __syncthreads();   // buffers dead from here; Tr takes over the storage
#pragma unroll
  for (int mt = 0; mt < 4; mt++){
    int e0 = eh + mt*16 + quad*4;
#pragma unroll
    for (int nt = 0; nt < 4; nt++){
      int c = nh + nt*16 + lane15;
      f32x4 v = acc[mt][nt];
      if (is_p){ v.x = __expf(v.x); v.y = __expf(v.y); v.z = __expf(v.z); v.w = __expf(v.w); }
      int p01 = __builtin_amdgcn_cvt_pk_fp8_f32(v.x, v.y, 0, false);
      int p23 = __builtin_amdgcn_cvt_pk_fp8_f32(v.z, v.w, 0, false);
      unsigned pk = ((unsigned)p01 & 0xFFFFu) | ((unsigned)p23 << 16);
      *(unsigned*)&sh.Tr[c][e0] = pk;
    }
  }
  __syncthreads();
  u8* dst = is_p ? (PT + ((size_t)bg*512 + (n0 - 256))*EPAD)
                 : (VT + ((size_t)bg*256 + n0)*EPAD);
  const int chalf = lane >> 5;
  const int e4 = (lane & 31) * 4;
#pragma unroll
  for (int i = 0; i < 16; i++){
    int c = wv*32 + i*2 + chalf;
    unsigned val = *(const unsigned*)&sh.Tr[c][e4];
    *(unsigned*)(dst + (size_t)c*EPAD + row0 + e4) = val;
  }
}

// PV reduction (fp8 MFMA): O^T[dh][l] = sum_e V[dh][e]*P[l][e]; den via ones-MFMA.
// grid (NCH2, 8, gb), 256 thr; each wave owns a 256-event K-slice.
__global__ __launch_bounds__(256) void k_b(
    const u8* __restrict__ PT, const u8* __restrict__ VT,
    const int* __restrict__ cnt, float* __restrict__ pnum, float* __restrict__ pden, int b0)
{
  __shared__ float red[4][2048];
  __shared__ float redd[4][64];
  const int t = threadIdx.x;
  const int wv = t >> 6, lane = t & 63;
  const int quad = lane >> 4, lane15 = lane & 15;
  const int chunk = blockIdx.x, h = blockIdx.y, bg = blockIdx.z;
  const int b = b0 + bg;
  const int cn = min(cnt[b], EMAXC);
  const u8* PTg = PT + ((size_t)bg*512 + h*64)*EPAD;
  const u8* VTg = VT + ((size_t)bg*256 + h*32)*EPAD;

  f32x4 acc[3][4];
#pragma unroll
  for (int i = 0; i < 3; i++)
#pragma unroll
    for (int j = 0; j < 4; j++) acc[i][j] = (f32x4){0.f,0.f,0.f,0.f};

  const long ones = 0x3838383838383838L;

  const int e0w = chunk*1024 + wv*256;
#pragma unroll 2
  for (int ks = 0; ks < 8; ks++){
    int eb = e0w + ks*32 + quad*8;
    long a0 = *(const long*)(VTg + (size_t)(lane15     )*EPAD + eb);
    long a1 = *(const long*)(VTg + (size_t)(16 + lane15)*EPAD + eb);
    long bp[4];
#pragma unroll
    for (int nt = 0; nt < 4; nt++){
      union { long v; u8 c[8]; } m;
      m.v = *(const long*)(PTg + (size_t)(nt*16 + lane15)*EPAD + eb);
      if (eb + 8 > cn){
#pragma unroll
        for (int j = 0; j < 8; j++) if (eb + j >= cn) m.c[j] = 0;
      }
      bp[nt] = m.v;
    }
#pragma unroll
    for (int nt = 0; nt < 4; nt++){
      acc[0][nt] = __builtin_amdgcn_mfma_f32_16x16x32_fp8_fp8(a0, bp[nt], acc[0][nt], 0, 0, 0);
      acc[1][nt] = __builtin_amdgcn_mfma_f32_16x16x32_fp8_fp8(a1, bp[nt], acc[1][nt], 0, 0, 0);
      acc[2][nt] = __builtin_amdgcn_mfma_f32_16x16x32_fp8_fp8(ones, bp[nt], acc[2][nt], 0, 0, 0);
    }
  }
#pragma unroll
  for (int mt = 0; mt < 2; mt++)
#pragma unroll
    for (int nt = 0; nt < 4; nt++){
      int l = nt*16 + lane15;
#pragma unroll
      for (int j = 0; j < 4; j++)
        red[wv][l*32 + mt*16 + quad*4 + j] = acc[mt][nt][j];
    }
  if (quad == 0){
#pragma unroll
    for (int nt = 0; nt < 4; nt++) redd[wv][nt*16 + lane15] = acc[2][nt][0];
  }
  __syncthreads();
  size_t obase = ((size_t)(b*NHH + h)*NCH2 + chunk);
  for (int i = t; i < 2048; i += 256)
    pnum[obase*2048 + i] = red[0][i] + red[1][i] + red[2][i] + red[3][i];
  if (t < 64)
    pden[obase*64 + t] = redd[0][t] + redd[1][t] + redd[2][t] + redd[3][t];
}

// Reduce partials over chunks, divide, write OC[b][l][h*32+dh]
__global__ void k_red(const float* __restrict__ pnum, const float* __restrict__ pden,
                      float* __restrict__ OC){
  int g = blockIdx.x*256 + threadIdx.x;
  int b = g >> 14, r = g & 16383;
  int h = r >> 11, idx = r & 2047;
  int l = idx >> 5, dh = idx & 31;
  float ns = 0.f, ds = 0.f;
  for (int c = 0; c < NCH2; c++){
    size_t ob = ((size_t)(b*NHH + h)*NCH2 + c);
    ns += pnum[ob*2048 + idx];
    ds += pden[ob*64 + l];
  }
  OC[((size_t)(b*NLAT + l))*DIMD + h*32 + dh] = ns/ds;
}

// Self-attention over 64 latents, one block per (batch, head)
__global__ __launch_bounds__(256) void k_attn(const float* __restrict__ qkv,
                                              float* __restrict__ outp){
  int b = blockIdx.x, h = blockIdx.y;
  __shared__ float qs[64][33], ks[64][33], vs[64][33];
  __shared__ float S[64][65];
  int t = threadIdx.x;
#pragma unroll
  for (int i = 0; i < 8; i++){
    int idx = t + i*256;
    int l = idx >> 5, d = idx & 31;
    const float* base = qkv + ((size_t)(b*NLAT + l))*768 + h*32 + d;
    qs[l][d] = base[0];
    ks[l][d] = base[256];
    vs[l][d] = base[512];
  }
  __syncthreads();
  const float scale = 0.1767766952966369f;
#pragma unroll
  for (int i = 0; i < 16; i++){
    int idx = t + i*256;
    int r = idx >> 6, c = idx & 63;
    float s = 0.f;
#pragma unroll
    for (int d = 0; d < 32; d++) s += qs[r][d]*ks[c][d];
    S[r][c] = s*scale;
  }
  __syncthreads();
  if (t < 64){
    float mx = -1e30f;
    for (int c = 0; c < 64; c++) mx = fmaxf(mx, S[t][c]);
    float sum = 0.f;
    for (int c = 0; c < 64; c++){ float p = expf(S[t][c] - mx); S[t][c] = p; sum += p; }
    float inv = 1.0f/sum;
    for (int c = 0; c < 64; c++) S[t][c] *= inv;
  }
  __syncthreads();
#pragma unroll
  for (int i = 0; i < 8; i++){
    int idx = t + i*256;
    int r = idx >> 5, d = idx & 31;
    float o = 0.f;
#pragma unroll
    for (int c = 0; c < 64; c++) o += S[r][c]*vs[c][d];
    outp[((size_t)(b*NLAT + r))*DIMD + h*32 + d] = o;
  }
}

// Behavior decoder attention + projection; one block per batch
__global__ void k_behav(const float* __restrict__ qb, const float* __restrict__ kv,
                        const float* __restrict__ wo, float* __restrict__ outp){
  int b = blockIdx.x;
  __shared__ float S[16][65];
  __shared__ float O2[2][256];
  __shared__ float red[256];
  int t = threadIdx.x;
  const float scale = 0.1767766952966369f;
#pragma unroll
  for (int i = 0; i < 4; i++){
    int idx = t + i*256;
    int row = idx >> 6, c = idx & 63;
    int iq = row >> 3, h = row & 7;
    const float* qp = qb + iq*DIMD + h*32;
    const float* kp = kv + ((size_t)(b*NLAT + c))*512 + h*32;
    float s = 0.f;
#pragma unroll
    for (int d = 0; d < 32; d++) s += qp[d]*kp[d];
    S[row][c] = s*scale;
  }
  __syncthreads();
  if (t < 16){
    float mx = -1e30f;
    for (int c = 0; c < 64; c++) mx = fmaxf(mx, S[t][c]);
    float sum = 0.f;
    for (int c = 0; c < 64; c++){ float p = expf(S[t][c] - mx); S[t][c] = p; sum += p; }
    float inv = 1.0f/sum;
    for (int c = 0; c < 64; c++) S[t][c] *= inv;
  }
  __syncthreads();
#pragma unroll
  for (int i = 0; i < 2; i++){
    int idx = t + i*256;
    int iq = idx >> 8, c2 = idx & 255;
    int h = c2 >> 5, d = c2 & 31;
    float o = 0.f;
    for (int c = 0; c < 64; c++)
      o += S[iq*8 + h][c]*kv[((size_t)(b*NLAT + c))*512 + 256 + h*32 + d];
    O2[iq][c2] = o;
  }
  __syncthreads();
  for (int iq = 0; iq < 2; iq++){
    red[t] = O2[iq][t]*wo[t];
    __syncthreads();
    for (int off = 128; off > 0; off >>= 1){
      if (t < off) red[t] += red[t + off];
      __syncthreads();
    }
    if (t == 0) outp[b*2 + iq] = red[0];
    __syncthreads();
  }
}

// Spike head: logits = mean_l(lat) @ sp_w + sp_b; one block per batch
__global__ void k_logits(const float* __restrict__ lat, const float* __restrict__ spw,
                         const float* __restrict__ spb, float* __restrict__ outp){
  int b = blockIdx.x;
  __shared__ float m[256];
  int t = threadIdx.x;
  float s = 0.f;
  for (int l = 0; l < NLAT; l++) s += lat[((size_t)(b*NLAT + l))*DIMD + t];
  m[t] = s*(1.0f/NLAT);
  __syncthreads();
  if (t < 64){
    float o = spb[t];
    for (int c = 0; c < 256; c++) o += m[c]*spw[c*64 + t];
    outp[32 + b*64 + t] = o;
  }
}

extern "C" void kernel_launch(void* const* d_in, const int* in_sizes, int n_in,
                              void* d_out, int out_size, void* d_ws, size_t ws_size,
                              hipStream_t stream){
  const int* nid      = (const int*)d_in[0];
  const int* tbin     = (const int*)d_in[1];
  const int* vval     = (const int*)d_in[2];
  const int* bidx     = (const int*)d_in[3];
  const float* ne     = (const float*)d_in[6];
  const float* te     = (const float*)d_in[7];
  const float* ve     = (const float*)d_in[8];
  const float* lat_i  = (const float*)d_in[9];
  const float* Wq_c   = (const float*)d_in[10];
  const float* Wkv_c  = (const float*)d_in[11];
  const float* Wo_c   = (const float*)d_in[12];
  const float* W1_c   = (const float*)d_in[13];
  const float* W2_c   = (const float*)d_in[14];
  const float* Wqkv_s = (const float*)d_in[15];
  const float* Wo_s   = (const float*)d_in[16];
  const float* W1_s   = (const float*)d_in[17];
  const float* W2_s   = (const float*)d_in[18];
  const float* bh_query = (const float*)d_in[19];
  const float* bh_wq    = (const float*)d_in[20];
  const float* bh_wkv   = (const float*)d_in[21];
  const float* bh_wo    = (const float*)d_in[22];
  const float* bh_ln_w  = (const float*)d_in[23];
  const float* bh_ln_b  = (const float*)d_in[24];
  const float* sp_w     = (const float*)d_in[25];
  const float* sp_b     = (const float*)d_in[26];
  float* out = (float*)d_out;
  int E = in_sizes[0];
  (void)n_in; (void)out_size;

  const size_t MBf = (size_t)1 << 20;
  size_t per_gb = (size_t)19*MBf;
  size_t fixed  = (size_t)29*MBf;
  int gb = 1;
  if      (fixed + 16*per_gb <= ws_size) gb = 16;
  else if (fixed +  8*per_gb <= ws_size) gb = 8;
  else if (fixed +  4*per_gb <= ws_size) gb = 4;
  else if (fixed +  2*per_gb <= ws_size) gb = 2;

  char* wsb = (char*)d_ws;
  size_t o = 0;
  auto alloc = [&](size_t bytes)->char*{
    char* p = wsb + o; o = (o + bytes + 255) & ~(size_t)255; return p;
  };
  int*   cnt    = (int*)  alloc((size_t)NB*4);
  int*   sorted = (int*)  alloc((size_t)NB*EMAXC*4);
  float* tq     = (float*)alloc((size_t)64*256*4);
  float* qc     = (float*)alloc((size_t)64*256*4);
  float* qb     = (float*)alloc((size_t)2*256*4);
  u16*   Wt     = (u16*)  alloc((size_t)768*256*2);
  u16*   XLN    = (u16*)  alloc((size_t)gb*EMAXC*256*2);
  u8*    PT     = (u8*)   alloc((size_t)gb*512*EPAD);
  u8*    VT     = (u8*)   alloc((size_t)gb*256*EPAD);
  float* pnum   = (float*)alloc((size_t)NB*NHH*NCH2*2048*4);
  float* pden   = (float*)alloc((size_t)NB*NHH*NCH2*64*4);
  float* OC     = (float*)alloc((size_t)NB*64*256*4);
  float* lat    = (float*)alloc((size_t)NB*64*256*4);
  float* qkv    = (float*)alloc((size_t)NB*64*768*4);
  float* ffh    = (float*)alloc((size_t)NB*64*1024*4);

  // ---- prep ----
  k_zero<<<1, 64, 0, stream>>>(cnt);
  k_sort<<<(E + 1023)/1024, 256, 0, stream>>>(bidx, cnt, sorted, E);
  k_ln<<<16, 256, 0, stream>>>(lat_i, tq, 64);
  k_gemm<<<dim3(8,1), 256, 0, stream>>>(tq, Wq_c, qc, 64, 256, 256);
  k_qw<<<768, 256, 0, stream>>>(Wkv_c, qc, Wt);
  k_gemm<<<dim3(1,1), 256, 0, stream>>>(bh_query, bh_wq, qb, 2, 256, 256);

  // ---- event cross-attention, runtime-sized batch groups ----
  for (int b0 = 0; b0 < NB; b0 += gb){
    k_a0<<<dim3(EMAXC/4, gb), 256, 0, stream>>>(sorted, cnt, nid, tbin, vval,
                                                ne, te, ve, XLN, b0);
    k_a<<<dim3(48, 14, gb), 256, 0, stream>>>(XLN, Wt, cnt, PT, VT, b0);
    k_b<<<dim3(NCH2, NHH, gb), 256, 0, stream>>>(PT, VT, cnt, pnum, pden, b0);
  }
  k_red<<<1024, 256, 0, stream>>>(pnum, pden, OC);

  // ---- latent chain (tiled f32 GEMMs; LN fused as prologue where K=256) ----
  const int M = NB*NLAT;  // 1024
  k_init<<<M, 256, 0, stream>>>(lat_i, lat);
  k_gemm2<<<dim3(16,4,4), 256, 0, stream>>>(OC, Wo_c, lat, nullptr, nullptr,
                                            M, 256, 256, 2, 0);
  k_gemm2<<<dim3(16,16,1), 256, 0, stream>>>(lat, W1_c, ffh, nullptr, nullptr,
                                             M, 256, 1024, 1, 1);
  k_gemm2<<<dim3(16,4,4), 256, 0, stream>>>(ffh, W2_c, lat, nullptr, nullptr,
                                            M, 1024, 256, 2, 0);

  for (int i = 0; i < 2; i++){
    k_gemm2<<<dim3(16,12,1), 256, 0, stream>>>(lat, Wqkv_s + (size_t)i*256*768, qkv,
                                               nullptr, nullptr, M, 256, 768, 0, 1);
    k_attn<<<dim3(NB, NHH), 256, 0, stream>>>(qkv, ffh);
    k_gemm2<<<dim3(16,4,4), 256, 0, stream>>>(ffh, Wo_s + (size_t)i*256*256, lat,
                                              nullptr, nullptr, M, 256, 256, 2, 0);
    k_gemm2<<<dim3(16,16,1), 256, 0, stream>>>(lat, W1_s + (size_t)i*256*1024, ffh,
                                               nullptr, nullptr, M, 256, 1024, 1, 1);
    k_gemm2<<<dim3(16,4,4), 256, 0, stream>>>(ffh, W2_s + (size_t)i*1024*256, lat,
                                              nullptr, nullptr, M, 1024, 256, 2, 0);
  }

  // ---- heads ----
  k_gemm2<<<dim3(16,8,1), 256, 0, stream>>>(lat, bh_wkv, qkv, bh_ln_w, bh_ln_b,
                                            M, 256, 512, 0, 1);
  k_behav<<<NB, 256, 0, stream>>>(qb, qkv, bh_wo, out);
  k_logits<<<NB, 256, 0, stream>>>(lat, sp_w, sp_b, out);
}

// Round 12
// 808.055 us; speedup vs baseline: 1.4164x; 1.4164x over previous
//
#include <hip/hip_runtime.h>
#include <math.h>

#define NB 16
#define DIMD 256
#define NHH 8
#define NLAT 64
#define EMAXC 13568
#define NCH2 14            /* chunks of 1024 events (last partial) */
#define EPAD (NCH2*1024)   /* 14336: padded event stride (bytes for fp8 PT/VT) */

typedef float f32x4 __attribute__((ext_vector_type(4)));
typedef __bf16 bf16x8 __attribute__((ext_vector_type(8)));
typedef unsigned short u16;
typedef unsigned char u8;
typedef __attribute__((ext_vector_type(8))) unsigned short u16x8;

static __device__ __forceinline__ float wave_sum(float v){
#pragma unroll
  for (int off = 32; off > 0; off >>= 1) v += __shfl_xor(v, off, 64);
  return v;
}

static __device__ __forceinline__ u16 f2bf(float x){
  unsigned u = __float_as_uint(x);
  u += 0x7fffu + ((u >> 16) & 1u);
  return (u16)(u >> 16);
}

static __device__ __forceinline__ float gelu_tanh(float x){
  float x3 = x*x*x;
  return 0.5f*x*(1.0f + tanhf(0.7978845608028654f*(x + 0.044715f*x3)));
}

__global__ void k_zero(int* cnt){ if ((int)threadIdx.x < NB) cnt[threadIdx.x] = 0; }

// LDS-histogram bucket sort: 16 global atomics per 1024-event block.
__global__ void k_sort(const int* __restrict__ bidx, int* __restrict__ cnt,
                       int* __restrict__ sorted, int E){
  __shared__ int h[NB], base[NB];
  int t = threadIdx.x;
  if (t < NB) h[t] = 0;
  __syncthreads();
  int e0 = blockIdx.x*1024;
  int myb[4], myp[4];
#pragma unroll
  for (int i = 0; i < 4; i++){
    int e = e0 + i*256 + t;
    myb[i] = -1;
    if (e < E){ myb[i] = bidx[e]; myp[i] = atomicAdd(&h[myb[i]], 1); }
  }
  __syncthreads();
  if (t < NB) base[t] = atomicAdd(&cnt[t], h[t]);
  __syncthreads();
#pragma unroll
  for (int i = 0; i < 4; i++){
    if (myb[i] >= 0){
      int p = base[myb[i]] + myp[i];
      if (p < EMAXC) sorted[myb[i]*EMAXC + p] = e0 + i*256 + t;
    }
  }
}

// LayerNorm over rows of 256 (used only for lat_init prep).
__global__ void k_ln(const float* __restrict__ X, float* __restrict__ Y, int rows){
  int wave = threadIdx.x >> 6, lane = threadIdx.x & 63;
  int row = blockIdx.x*4 + wave;
  if (row >= rows) return;
  float4 x = ((const float4*)(X + (size_t)row*DIMD))[lane];
  float s = wave_sum(x.x + x.y + x.z + x.w);
  float m = s * (1.0f/DIMD);
  float d0 = x.x-m, d1 = x.y-m, d2 = x.z-m, d3 = x.w-m;
  float v = wave_sum(d0*d0 + d1*d1 + d2*d2 + d3*d3) * (1.0f/DIMD);
  float rs = rsqrtf(v + 1e-5f);
  ((float4*)(Y + (size_t)row*DIMD))[lane] = make_float4(d0*rs, d1*rs, d2*rs, d3*rs);
}

// lat[row] = lat_init[row % 64]  (row-broadcast residual init)
__global__ void k_init(const float* __restrict__ lat_i, float* __restrict__ lat){
  int r = blockIdx.x, t = threadIdx.x;
  lat[(size_t)r*DIMD + t] = lat_i[(size_t)(r & 63)*DIMD + t];
}

// Small prep GEMM (tiny M): C[M,N] = A[M,K] @ W[K,N]
__global__ __launch_bounds__(256) void k_gemm(
    const float* __restrict__ A, const float* __restrict__ W,
    float* __restrict__ C, int M, int K, int N){
  __shared__ float As[8][1024];
  int t = threadIdx.x;
  int row0 = blockIdx.x*8;
  int col = blockIdx.y*256 + t;
  int kq = K >> 2;
  for (int idx = t; idx < 8*kq; idx += 256){
    int r = idx / kq, kc = idx % kq;
    float4 v = make_float4(0.f,0.f,0.f,0.f);
    if (row0 + r < M) v = ((const float4*)(A + (size_t)(row0+r)*K))[kc];
    ((float4*)&As[r][0])[kc] = v;
  }
  __syncthreads();
  float acc[8] = {0,0,0,0,0,0,0,0};
  for (int k = 0; k < K; k += 4){
    float w0 = W[(size_t)(k+0)*N + col];
    float w1 = W[(size_t)(k+1)*N + col];
    float w2 = W[(size_t)(k+2)*N + col];
    float w3 = W[(size_t)(k+3)*N + col];
#pragma unroll
    for (int r = 0; r < 8; r++){
      float4 a = *((const float4*)&As[r][k]);
      acc[r] += a.x*w0 + a.y*w1 + a.z*w2 + a.w*w3;
    }
  }
#pragma unroll
  for (int r = 0; r < 8; r++){
    int row = row0 + r;
    if (row < M) C[(size_t)row*N + col] = acc[r];
  }
}

// Tiled f32 GEMM for the latent chain. 64x64 tile, BK=32, 256 thr, 4x4/thread.
// grid (M/64, N/64, S): K split into S chunks.
// mode 0: C = A@W ; 1: gelu ; 2: atomicAdd(C, A@W).
// do_ln (requires K==256, S==1): LayerNorm rows of A (optional affine lnw/lnb).
__global__ __launch_bounds__(256) void k_gemm2(
    const float* __restrict__ A, const float* __restrict__ W, float* __restrict__ C,
    const float* __restrict__ lnw, const float* __restrict__ lnb,
    int M, int K, int N, int mode, int do_ln){
  __shared__ float As[32][66];
  __shared__ float Bs[32][66];
  __shared__ float lnm[64], lnr[64];
  const int t = threadIdx.x;
  const int m0 = blockIdx.x*64, n0 = blockIdx.y*64;
  const int Kc = K / gridDim.z;
  const int k0b = blockIdx.z*Kc;
  const int ty = t >> 4, tx = t & 15;
  float acc[4][4];
#pragma unroll
  for (int i = 0; i < 4; i++)
#pragma unroll
    for (int j = 0; j < 4; j++) acc[i][j] = 0.f;

  if (do_ln){
    int r = t >> 2, seg = (t & 3)*64;
    const float* Ar = A + (size_t)(m0 + r)*K + seg;
    float s = 0.f, s2 = 0.f;
#pragma unroll
    for (int j = 0; j < 64; j += 4){
      float4 v = *(const float4*)(Ar + j);
      s  += v.x + v.y + v.z + v.w;
      s2 += v.x*v.x + v.y*v.y + v.z*v.z + v.w*v.w;
    }
    s += __shfl_xor(s, 1, 64); s2 += __shfl_xor(s2, 1, 64);
    s += __shfl_xor(s, 2, 64); s2 += __shfl_xor(s2, 2, 64);
    if ((t & 3) == 0){
      float m = s*(1.0f/256.0f);
      float var = s2*(1.0f/256.0f) - m*m;
      lnm[r] = m; lnr[r] = rsqrtf(var + 1e-5f);
    }
  }
  if (do_ln) __syncthreads();

  for (int k0 = k0b; k0 < k0b + Kc; k0 += 32){
    __syncthreads();
#pragma unroll
    for (int p = 0; p < 2; p++){
      int li = t + p*256;
      int r = li >> 3, kc = li & 7;
      float4 va = *(const float4*)(A + (size_t)(m0+r)*K + k0 + kc*4);
      if (do_ln){
        float m = lnm[r], rs = lnr[r];
        va.x = (va.x - m)*rs; va.y = (va.y - m)*rs;
        va.z = (va.z - m)*rs; va.w = (va.w - m)*rs;
        if (lnw){
          int k = k0 + kc*4;
          va.x = va.x*lnw[k+0] + lnb[k+0];
          va.y = va.y*lnw[k+1] + lnb[k+1];
          va.z = va.z*lnw[k+2] + lnb[k+2];
          va.w = va.w*lnw[k+3] + lnb[k+3];
        }
      }
      As[kc*4+0][r] = va.x; As[kc*4+1][r] = va.y;
      As[kc*4+2][r] = va.z; As[kc*4+3][r] = va.w;
      int kr = li >> 4, nc = li & 15;
      *(float4*)&Bs[kr][nc*4] = *(const float4*)(W + (size_t)(k0+kr)*N + n0 + nc*4);
    }
    __syncthreads();
#pragma unroll
    for (int k = 0; k < 32; k++){
      float4 a = *(const float4*)&As[k][ty*4];
      float4 b = *(const float4*)&Bs[k][tx*4];
      acc[0][0] += a.x*b.x; acc[0][1] += a.x*b.y; acc[0][2] += a.x*b.z; acc[0][3] += a.x*b.w;
      acc[1][0] += a.y*b.x; acc[1][1] += a.y*b.y; acc[1][2] += a.y*b.z; acc[1][3] += a.y*b.w;
      acc[2][0] += a.z*b.x; acc[2][1] += a.z*b.y; acc[2][2] += a.z*b.z; acc[2][3] += a.z*b.w;
      acc[3][0] += a.w*b.x; acc[3][1] += a.w*b.y; acc[3][2] += a.w*b.z; acc[3][3] += a.w*b.w;
    }
  }
#pragma unroll
  for (int i = 0; i < 4; i++){
    int row = m0 + ty*4 + i;
    float* crow = C + (size_t)row*N + n0 + tx*4;
#pragma unroll
    for (int j = 0; j < 4; j++){
      float v = acc[i][j];
      if (mode == 1) v = gelu_tanh(v);
      if (mode == 2) atomicAdd(&crow[j], v);
      else crow[j] = v;
    }
  }
}

// Build Wt[768][256] bf16 (transposed, column-reordered)
__global__ void k_qw(const float* __restrict__ Wkv, const float* __restrict__ qc,
                     u16* __restrict__ Wt){
  int n = blockIdx.x;
  int k = threadIdx.x;
  float v;
  if (n < 256){
    v = Wkv[(size_t)k*512 + 256 + n];
  } else {
    int h = (n - 256) >> 6, l = (n - 256) & 63;
    const float* wk = Wkv + (size_t)k*512 + h*32;
    const float* qr = qc + (size_t)l*256 + h*32;
    float s = 0.f;
#pragma unroll
    for (int dd = 0; dd < 32; dd++) s += wk[dd]*qr[dd];
    v = s*0.1767766952966369f;
  }
  Wt[(size_t)n*256 + k] = f2bf(v);
}

// Gather+LN -> XLN bf16 (group-local), zero pad rows. One wave per event row.
__global__ void k_a0(const int* __restrict__ sorted, const int* __restrict__ cnt,
                     const int* __restrict__ nid, const int* __restrict__ tbin,
                     const int* __restrict__ vval,
                     const float* __restrict__ ne, const float* __restrict__ te,
                     const float* __restrict__ ve, u16* __restrict__ XLN, int b0){
  int wv = threadIdx.x >> 6, lane = threadIdx.x & 63;
  int e = blockIdx.x*4 + wv;
  int bg = blockIdx.y, b = b0 + bg;
  int cn = min(cnt[b], EMAXC);
  ushort4 pk; pk.x = 0; pk.y = 0; pk.z = 0; pk.w = 0;
  if (e < cn){
    int ev = sorted[b*EMAXC + e];
    float4 aa = ((const float4*)(ne + (size_t)nid[ev]*DIMD))[lane];
    float4 bb = ((const float4*)(te + (size_t)tbin[ev]*DIMD))[lane];
    float4 cc = ((const float4*)(ve + (size_t)vval[ev]*DIMD))[lane];
    float x0 = aa.x+bb.x+cc.x, x1 = aa.y+bb.y+cc.y;
    float x2 = aa.z+bb.z+cc.z, x3 = aa.w+bb.w+cc.w;
    float s = wave_sum(x0 + x1 + x2 + x3);
    float m = s*(1.0f/DIMD);
    x0 -= m; x1 -= m; x2 -= m; x3 -= m;
    float v = wave_sum(x0*x0 + x1*x1 + x2*x2 + x3*x3)*(1.0f/DIMD);
    float rs = rsqrtf(v + 1e-5f);
    pk.x = f2bf(x0*rs); pk.y = f2bf(x1*rs); pk.z = f2bf(x2*rs); pk.w = f2bf(x3*rs);
  }
  *(ushort4*)(XLN + ((size_t)bg*EMAXC + e)*DIMD + lane*4) = pk;
}

// Dense MFMA GEMM: [PT|VT] (transposed, fp8 e4m3) = exp?(XLN @ Wt^T).
// 128x128 tile, BK=32 double-buffered (register prefetch -> ping-pong LDS,
// ONE barrier per K-step). Pitch 40 u16 = 80 B: rows 16B-aligned (b128 keeps),
// start bank 20r mod 32 distinct over 8 rows -> fragment reads 2-way (free).
// LDS 40 KB -> 4 blocks/CU. Tr overlays the buffers.
// grid (48, 14, gb), XCD-affinity swizzle.
__global__ __launch_bounds__(256) void k_a(
    const u16* __restrict__ XLN, const u16* __restrict__ Wt,
    const int* __restrict__ cnt, u8* __restrict__ PT, u8* __restrict__ VT, int b0)
{
  __shared__ union ShMem {
    struct { u16 Xs[2][128][40]; u16 Ws[2][128][40]; } s;
    u8 Tr[128][136];
  } sh;
  const int t = threadIdx.x;
  const int wv = t >> 6, lane = t & 63;
  const int quad = lane >> 4, lane15 = lane & 15;
  const int nidx = blockIdx.x >> 3;
  const int rtile = blockIdx.y*8 + (blockIdx.x & 7);
  if (nidx >= 6 || rtile >= EMAXC/128) return;
  const int bg = blockIdx.z;
  const int b = b0 + bg;
  const int cn = min(cnt[b], EMAXC);
  const int row0 = rtile * 128;
  if (row0 >= cn) return;
  const int n0 = nidx * 128;
  const int eh = (wv >> 1) * 64, nh = (wv & 1) * 64;

  f32x4 acc[4][4];
#pragma unroll
  for (int i = 0; i < 4; i++)
#pragma unroll
    for (int j = 0; j < 4; j++) acc[i][j] = (f32x4){0.f,0.f,0.f,0.f};

  const u16* Xbase = XLN + ((size_t)bg*EMAXC + row0)*DIMD;
  const u16* Wbase = Wt + (size_t)n0*256;

  u16x8 xv[2], wvv[2];
  auto gload = [&](int k0){
#pragma unroll
    for (int p = 0; p < 2; p++){
      int li = p*256 + t;
      int r = li >> 2, kc = li & 3;
      xv[p]  = *(const u16x8*)(Xbase + (size_t)r*DIMD + k0 + kc*8);
      wvv[p] = *(const u16x8*)(Wbase + (size_t)r*256  + k0 + kc*8);
    }
  };
  auto sstore = [&](int buf){
#pragma unroll
    for (int p = 0; p < 2; p++){
      int li = p*256 + t;
      int r = li >> 2, kc = li & 3;
      *(u16x8*)&sh.s.Xs[buf][r][kc*8] = xv[p];
      *(u16x8*)&sh.s.Ws[buf][r][kc*8] = wvv[p];
    }
  };
  auto compute = [&](int buf){
    bf16x8 a[4], bw[4];
#pragma unroll
    for (int mt = 0; mt < 4; mt++)
      a[mt] = *(const bf16x8*)&sh.s.Xs[buf][eh + mt*16 + lane15][quad*8];
#pragma unroll
    for (int nt = 0; nt < 4; nt++)
      bw[nt] = *(const bf16x8*)&sh.s.Ws[buf][nh + nt*16 + lane15][quad*8];
#pragma unroll
    for (int mt = 0; mt < 4; mt++)
#pragma unroll
      for (int nt = 0; nt < 4; nt++)
        acc[mt][nt] = __builtin_amdgcn_mfma_f32_16x16x32_bf16(a[mt], bw[nt], acc[mt][nt], 0, 0, 0);
  };

  gload(0);
  sstore(0);
#pragma unroll
  for (int it = 0; it < 8; it++){
    int buf = it & 1;
    if (it < 7) gload((it + 1)*32);
    __syncthreads();          // buf's stores visible; all waves done with compute(it-1)
    compute(buf);
    if (it < 7) sstore(1 - buf);
  }
  const int is_p = (n0 >= 256);
  __syncthreads();   // buffers dead from here; Tr takes over the storage
#pragma unroll
  for (int mt = 0; mt < 4; mt++){
    int e0 = eh + mt*16 + quad*4;
#pragma unroll
    for (int nt = 0; nt < 4; nt++){
      int c = nh + nt*16 + lane15;
      f32x4 v = acc[mt][nt];
      if (is_p){ v.x = __expf(v.x); v.y = __expf(v.y); v.z = __expf(v.z); v.w = __expf(v.w); }
      int p01 = __builtin_amdgcn_cvt_pk_fp8_f32(v.x, v.y, 0, false);
      int p23 = __builtin_amdgcn_cvt_pk_fp8_f32(v.z, v.w, 0, false);
      unsigned pk = ((unsigned)p01 & 0xFFFFu) | ((unsigned)p23 << 16);
      *(unsigned*)&sh.Tr[c][e0] = pk;
    }
  }
  __syncthreads();
  u8* dst = is_p ? (PT + ((size_t)bg*512 + (n0 - 256))*EPAD)
                 : (VT + ((size_t)bg*256 + n0)*EPAD);
  const int chalf = lane >> 5;
  const int e4 = (lane & 31) * 4;
#pragma unroll
  for (int i = 0; i < 16; i++){
    int c = wv*32 + i*2 + chalf;
    unsigned val = *(const unsigned*)&sh.Tr[c][e4];
    *(unsigned*)(dst + (size_t)c*EPAD + row0 + e4) = val;
  }
}

// PV reduction (fp8 MFMA): O^T[dh][l] = sum_e V[dh][e]*P[l][e]; den via ones-MFMA.
// grid (NCH2, 8, gb), 256 thr; each wave owns a 256-event K-slice.
__global__ __launch_bounds__(256) void k_b(
    const u8* __restrict__ PT, const u8* __restrict__ VT,
    const int* __restrict__ cnt, float* __restrict__ pnum, float* __restrict__ pden, int b0)
{
  __shared__ float red[4][2048];
  __shared__ float redd[4][64];
  const int t = threadIdx.x;
  const int wv = t >> 6, lane = t & 63;
  const int quad = lane >> 4, lane15 = lane & 15;
  const int chunk = blockIdx.x, h = blockIdx.y, bg = blockIdx.z;
  const int b = b0 + bg;
  const int cn = min(cnt[b], EMAXC);
  const u8* PTg = PT + ((size_t)bg*512 + h*64)*EPAD;
  const u8* VTg = VT + ((size_t)bg*256 + h*32)*EPAD;

  f32x4 acc[3][4];
#pragma unroll
  for (int i = 0; i < 3; i++)
#pragma unroll
    for (int j = 0; j < 4; j++) acc[i][j] = (f32x4){0.f,0.f,0.f,0.f};

  const long ones = 0x3838383838383838L;

  const int e0w = chunk*1024 + wv*256;
#pragma unroll 2
  for (int ks = 0; ks < 8; ks++){
    int eb = e0w + ks*32 + quad*8;
    long a0 = *(const long*)(VTg + (size_t)(lane15     )*EPAD + eb);
    long a1 = *(const long*)(VTg + (size_t)(16 + lane15)*EPAD + eb);
    long bp[4];
#pragma unroll
    for (int nt = 0; nt < 4; nt++){
      union { long v; u8 c[8]; } m;
      m.v = *(const long*)(PTg + (size_t)(nt*16 + lane15)*EPAD + eb);
      if (eb + 8 > cn){
#pragma unroll
        for (int j = 0; j < 8; j++) if (eb + j >= cn) m.c[j] = 0;
      }
      bp[nt] = m.v;
    }
#pragma unroll
    for (int nt = 0; nt < 4; nt++){
      acc[0][nt] = __builtin_amdgcn_mfma_f32_16x16x32_fp8_fp8(a0, bp[nt], acc[0][nt], 0, 0, 0);
      acc[1][nt] = __builtin_amdgcn_mfma_f32_16x16x32_fp8_fp8(a1, bp[nt], acc[1][nt], 0, 0, 0);
      acc[2][nt] = __builtin_amdgcn_mfma_f32_16x16x32_fp8_fp8(ones, bp[nt], acc[2][nt], 0, 0, 0);
    }
  }
#pragma unroll
  for (int mt = 0; mt < 2; mt++)
#pragma unroll
    for (int nt = 0; nt < 4; nt++){
      int l = nt*16 + lane15;
#pragma unroll
      for (int j = 0; j < 4; j++)
        red[wv][l*32 + mt*16 + quad*4 + j] = acc[mt][nt][j];
    }
  if (quad == 0){
#pragma unroll
    for (int nt = 0; nt < 4; nt++) redd[wv][nt*16 + lane15] = acc[2][nt][0];
  }
  __syncthreads();
  size_t obase = ((size_t)(b*NHH + h)*NCH2 + chunk);
  for (int i = t; i < 2048; i += 256)
    pnum[obase*2048 + i] = red[0][i] + red[1][i] + red[2][i] + red[3][i];
  if (t < 64)
    pden[obase*64 + t] = redd[0][t] + redd[1][t] + redd[2][t] + redd[3][t];
}

// Reduce partials over chunks, divide, write OC[b][l][h*32+dh]
__global__ void k_red(const float* __restrict__ pnum, const float* __restrict__ pden,
                      float* __restrict__ OC){
  int g = blockIdx.x*256 + threadIdx.x;
  int b = g >> 14, r = g & 16383;
  int h = r >> 11, idx = r & 2047;
  int l = idx >> 5, dh = idx & 31;
  float ns = 0.f, ds = 0.f;
  for (int c = 0; c < NCH2; c++){
    size_t ob = ((size_t)(b*NHH + h)*NCH2 + c);
    ns += pnum[ob*2048 + idx];
    ds += pden[ob*64 + l];
  }
  OC[((size_t)(b*NLAT + l))*DIMD + h*32 + dh] = ns/ds;
}

// Self-attention over 64 latents, one block per (batch, head)
__global__ __launch_bounds__(256) void k_attn(const float* __restrict__ qkv,
                                              float* __restrict__ outp){
  int b = blockIdx.x, h = blockIdx.y;
  __shared__ float qs[64][33], ks[64][33], vs[64][33];
  __shared__ float S[64][65];
  int t = threadIdx.x;
#pragma unroll
  for (int i = 0; i < 8; i++){
    int idx = t + i*256;
    int l = idx >> 5, d = idx & 31;
    const float* base = qkv + ((size_t)(b*NLAT + l))*768 + h*32 + d;
    qs[l][d] = base[0];
    ks[l][d] = base[256];
    vs[l][d] = base[512];
  }
  __syncthreads();
  const float scale = 0.1767766952966369f;
#pragma unroll
  for (int i = 0; i < 16; i++){
    int idx = t + i*256;
    int r = idx >> 6, c = idx & 63;
    float s = 0.f;
#pragma unroll
    for (int d = 0; d < 32; d++) s += qs[r][d]*ks[c][d];
    S[r][c] = s*scale;
  }
  __syncthreads();
  if (t < 64){
    float mx = -1e30f;
    for (int c = 0; c < 64; c++) mx = fmaxf(mx, S[t][c]);
    float sum = 0.f;
    for (int c = 0; c < 64; c++){ float p = expf(S[t][c] - mx); S[t][c] = p; sum += p; }
    float inv = 1.0f/sum;
    for (int c = 0; c < 64; c++) S[t][c] *= inv;
  }
  __syncthreads();
#pragma unroll
  for (int i = 0; i < 8; i++){
    int idx = t + i*256;
    int r = idx >> 5, d = idx & 31;
    float o = 0.f;
#pragma unroll
    for (int c = 0; c < 64; c++) o += S[r][c]*vs[c][d];
    outp[((size_t)(b*NLAT + r))*DIMD + h*32 + d] = o;
  }
}

// Behavior decoder attention + projection; one block per batch
__global__ void k_behav(const float* __restrict__ qb, const float* __restrict__ kv,
                        const float* __restrict__ wo, float* __restrict__ outp){
  int b = blockIdx.x;
  __shared__ float S[16][65];
  __shared__ float O2[2][256];
  __shared__ float red[256];
  int t = threadIdx.x;
  const float scale = 0.1767766952966369f;
#pragma unroll
  for (int i = 0; i < 4; i++){
    int idx = t + i*256;
    int row = idx >> 6, c = idx & 63;
    int iq = row >> 3, h = row & 7;
    const float* qp = qb + iq*DIMD + h*32;
    const float* kp = kv + ((size_t)(b*NLAT + c))*512 + h*32;
    float s = 0.f;
#pragma unroll
    for (int d = 0; d < 32; d++) s += qp[d]*kp[d];
    S[row][c] = s*scale;
  }
  __syncthreads();
  if (t < 16){
    float mx = -1e30f;
    for (int c = 0; c < 64; c++) mx = fmaxf(mx, S[t][c]);
    float sum = 0.f;
    for (int c = 0; c < 64; c++){ float p = expf(S[t][c] - mx); S[t][c] = p; sum += p; }
    float inv = 1.0f/sum;
    for (int c = 0; c < 64; c++) S[t][c] *= inv;
  }
  __syncthreads();
#pragma unroll
  for (int i = 0; i < 2; i++){
    int idx = t + i*256;
    int iq = idx >> 8, c2 = idx & 255;
    int h = c2 >> 5, d = c2 & 31;
    float o = 0.f;
    for (int c = 0; c < 64; c++)
      o += S[iq*8 + h][c]*kv[((size_t)(b*NLAT + c))*512 + 256 + h*32 + d];
    O2[iq][c2] = o;
  }
  __syncthreads();
  for (int iq = 0; iq < 2; iq++){
    red[t] = O2[iq][t]*wo[t];
    __syncthreads();
    for (int off = 128; off > 0; off >>= 1){
      if (t < off) red[t] += red[t + off];
      __syncthreads();
    }
    if (t == 0) outp[b*2 + iq] = red[0];
    __syncthreads();
  }
}

// Spike head: logits = mean_l(lat) @ sp_w + sp_b; one block per batch
__global__ void k_logits(const float* __restrict__ lat, const float* __restrict__ spw,
                         const float* __restrict__ spb, float* __restrict__ outp){
  int b = blockIdx.x;
  __shared__ float m[256];
  int t = threadIdx.x;
  float s = 0.f;
  for (int l = 0; l < NLAT; l++) s += lat[((size_t)(b*NLAT + l))*DIMD + t];
  m[t] = s*(1.0f/NLAT);
  __syncthreads();
  if (t < 64){
    float o = spb[t];
    for (int c = 0; c < 256; c++) o += m[c]*spw[c*64 + t];
    outp[32 + b*64 + t] = o;
  }
}

extern "C" void kernel_launch(void* const* d_in, const int* in_sizes, int n_in,
                              void* d_out, int out_size, void* d_ws, size_t ws_size,
                              hipStream_t stream){
  const int* nid      = (const int*)d_in[0];
  const int* tbin     = (const int*)d_in[1];
  const int* vval     = (const int*)d_in[2];
  const int* bidx     = (const int*)d_in[3];
  const float* ne     = (const float*)d_in[6];
  const float* te     = (const float*)d_in[7];
  const float* ve     = (const float*)d_in[8];
  const float* lat_i  = (const float*)d_in[9];
  const float* Wq_c   = (const float*)d_in[10];
  const float* Wkv_c  = (const float*)d_in[11];
  const float* Wo_c   = (const float*)d_in[12];
  const float* W1_c   = (const float*)d_in[13];
  const float* W2_c   = (const float*)d_in[14];
  const float* Wqkv_s = (const float*)d_in[15];
  const float* Wo_s   = (const float*)d_in[16];
  const float* W1_s   = (const float*)d_in[17];
  const float* W2_s   = (const float*)d_in[18];
  const float* bh_query = (const float*)d_in[19];
  const float* bh_wq    = (const float*)d_in[20];
  const float* bh_wkv   = (const float*)d_in[21];
  const float* bh_wo    = (const float*)d_in[22];
  const float* bh_ln_w  = (const float*)d_in[23];
  const float* bh_ln_b  = (const float*)d_in[24];
  const float* sp_w     = (const float*)d_in[25];
  const float* sp_b     = (const float*)d_in[26];
  float* out = (float*)d_out;
  int E = in_sizes[0];
  (void)n_in; (void)out_size;

  const size_t MBf = (size_t)1 << 20;
  size_t per_gb = (size_t)19*MBf;
  size_t fixed  = (size_t)29*MBf;
  int gb = 1;
  if      (fixed + 16*per_gb <= ws_size) gb = 16;
  else if (fixed +  8*per_gb <= ws_size) gb = 8;
  else if (fixed +  4*per_gb <= ws_size) gb = 4;
  else if (fixed +  2*per_gb <= ws_size) gb = 2;

  char* wsb = (char*)d_ws;
  size_t o = 0;
  auto alloc = [&](size_t bytes)->char*{
    char* p = wsb + o; o = (o + bytes + 255) & ~(size_t)255; return p;
  };
  int*   cnt    = (int*)  alloc((size_t)NB*4);
  int*   sorted = (int*)  alloc((size_t)NB*EMAXC*4);
  float* tq     = (float*)alloc((size_t)64*256*4);
  float* qc     = (float*)alloc((size_t)64*256*4);
  float* qb     = (float*)alloc((size_t)2*256*4);
  u16*   Wt     = (u16*)  alloc((size_t)768*256*2);
  u16*   XLN    = (u16*)  alloc((size_t)gb*EMAXC*256*2);
  u8*    PT     = (u8*)   alloc((size_t)gb*512*EPAD);
  u8*    VT     = (u8*)   alloc((size_t)gb*256*EPAD);
  float* pnum   = (float*)alloc((size_t)NB*NHH*NCH2*2048*4);
  float* pden   = (float*)alloc((size_t)NB*NHH*NCH2*64*4);
  float* OC     = (float*)alloc((size_t)NB*64*256*4);
  float* lat    = (float*)alloc((size_t)NB*64*256*4);
  float* qkv    = (float*)alloc((size_t)NB*64*768*4);
  float* ffh    = (float*)alloc((size_t)NB*64*1024*4);

  // ---- prep ----
  k_zero<<<1, 64, 0, stream>>>(cnt);
  k_sort<<<(E + 1023)/1024, 256, 0, stream>>>(bidx, cnt, sorted, E);
  k_ln<<<16, 256, 0, stream>>>(lat_i, tq, 64);
  k_gemm<<<dim3(8,1), 256, 0, stream>>>(tq, Wq_c, qc, 64, 256, 256);
  k_qw<<<768, 256, 0, stream>>>(Wkv_c, qc, Wt);
  k_gemm<<<dim3(1,1), 256, 0, stream>>>(bh_query, bh_wq, qb, 2, 256, 256);

  // ---- event cross-attention, runtime-sized batch groups ----
  for (int b0 = 0; b0 < NB; b0 += gb){
    k_a0<<<dim3(EMAXC/4, gb), 256, 0, stream>>>(sorted, cnt, nid, tbin, vval,
                                                ne, te, ve, XLN, b0);
    k_a<<<dim3(48, 14, gb), 256, 0, stream>>>(XLN, Wt, cnt, PT, VT, b0);
    k_b<<<dim3(NCH2, NHH, gb), 256, 0, stream>>>(PT, VT, cnt, pnum, pden, b0);
  }
  k_red<<<1024, 256, 0, stream>>>(pnum, pden, OC);

  // ---- latent chain (tiled f32 GEMMs; LN fused as prologue where K=256) ----
  const int M = NB*NLAT;  // 1024
  k_init<<<M, 256, 0, stream>>>(lat_i, lat);
  k_gemm2<<<dim3(16,4,4), 256, 0, stream>>>(OC, Wo_c, lat, nullptr, nullptr,
                                            M, 256, 256, 2, 0);
  k_gemm2<<<dim3(16,16,1), 256, 0, stream>>>(lat, W1_c, ffh, nullptr, nullptr,
                                             M, 256, 1024, 1, 1);
  k_gemm2<<<dim3(16,4,4), 256, 0, stream>>>(ffh, W2_c, lat, nullptr, nullptr,
                                            M, 1024, 256, 2, 0);

  for (int i = 0; i < 2; i++){
    k_gemm2<<<dim3(16,12,1), 256, 0, stream>>>(lat, Wqkv_s + (size_t)i*256*768, qkv,
                                               nullptr, nullptr, M, 256, 768, 0, 1);
    k_attn<<<dim3(NB, NHH), 256, 0, stream>>>(qkv, ffh);
    k_gemm2<<<dim3(16,4,4), 256, 0, stream>>>(ffh, Wo_s + (size_t)i*256*256, lat,
                                              nullptr, nullptr, M, 256, 256, 2, 0);
    k_gemm2<<<dim3(16,16,1), 256, 0, stream>>>(lat, W1_s + (size_t)i*256*1024, ffh,
                                               nullptr, nullptr, M, 256, 1024, 1, 1);
    k_gemm2<<<dim3(16,4,4), 256, 0, stream>>>(ffh, W2_s + (size_t)i*1024*256, lat,
                                              nullptr, nullptr, M, 1024, 256, 2, 0);
  }

  // ---- heads ----
  k_gemm2<<<dim3(16,8,1), 256, 0, stream>>>(lat, bh_wkv, qkv, bh_ln_w, bh_ln_b,
                                            M, 256, 512, 0, 1);
  k_behav<<<NB, 256, 0, stream>>>(qb, qkv, bh_wo, out);
  k_logits<<<NB, 256, 0, stream>>>(lat, sp_w, sp_b, out);
}